// Round 10
// baseline (229.062 us; speedup 1.0000x reference)
//
#include <hip/hip_runtime.h>

// GHM-C loss, two-pass: counts -> weighted sum -> tiny reduce.
// loss = sum_elem bce/(C_bin(elem) * n_nonempty);  weights need GLOBAL counts.
//
// R1: same-address device atomics -> cross-XCD bouncing -> per-block partials.
// R3: per-elem LDS RMW hist = 123us.  R5: register select tree = 76us.
// R6: FAILED ticket fusion.  R9: exec-mask tree neutral.  R10: native-trans
//   builtins bitwise-identical -> __expf/__logf were already native.
// R11 (counters): stripped counts kernel (14 instr/elem, VGPR=16) STILL 58us,
//   VALU 14.6%, HBM 18%. Wall = issue + ~110K-cyc constant floor across all
//   kernels. KEY: ghmc_wsum (more work, same arrays, L3-warm) ran FASTER than
//   counts -> floor = memory service time under tiny MLP (VGPR=16 => ~1-2 loads
//   in flight/wave; ~16KB outstanding/SIMD caps BW at ~2.9 TB/s by Little's law).
// R12 (this round): MLP maximization. Bench shape = exactly 10 vec4/thread ->
//   specialized fully-unrolled path issues ALL 20 loads up-front (fenced, can't
//   be sunk). VGPR ~100 (4 waves/SIMD) but 5x outstanding bytes. Element order
//   per thread unchanged -> counts exact, wsum order identical.

#define NBINS  10
#define GRID1  2048
#define BLOCK1 256

typedef float vf4 __attribute__((ext_vector_type(4)));
typedef int   vi4 __attribute__((ext_vector_type(4)));

#if __has_builtin(__builtin_amdgcn_exp2f)
__device__ __forceinline__ float nexp2(float a) { return __builtin_amdgcn_exp2f(a); }
#else
__device__ __forceinline__ float nexp2(float a) { return __expf(a * 0.69314718055994531f); }
#endif
#if __has_builtin(__builtin_amdgcn_logf)
__device__ __forceinline__ float nlog2(float a) { return __builtin_amdgcn_logf(a); }
#else
__device__ __forceinline__ float nlog2(float a) { return __logf(a) * 1.44269504088896341f; }
#endif

#define LOG2E 1.44269504088896341f
#define LN2   0.69314718055994531f

#define VPT 10   // vec4 per thread on the bench shape

__device__ __forceinline__ int binof(float x, float tf, float& z) {
    z = __builtin_amdgcn_rcpf(1.0f + nexp2(-x * LOG2E));   // sigmoid(x)
    float g = fabsf(z - tf);                               // [0,1]
    int bi = (int)(g * 10.0f);
    return bi > (NBINS - 1) ? (NBINS - 1) : bi;
}

// ---------------- Pass A: per-block bin counts ----------------
__global__ __launch_bounds__(BLOCK1) void ghmc_counts(
    const vf4* __restrict__ pred4,
    const vi4* __restrict__ targ4,
    int* __restrict__ partial_c,     // [NBINS][GRID1] bin-major
    int nvec4)
{
    __shared__ int cred[BLOCK1 / 64][NBINS];

    unsigned long long cnt = 0;   // 10 x 6-bit packed counts; max 40/bin/thread < 63

    const int idx    = blockIdx.x * BLOCK1 + threadIdx.x;
    const int stride = GRID1 * BLOCK1;

    if (nvec4 == VPT * stride) {
        // Specialized: all 20 loads issued up-front -> ~80 VGPR of data in
        // flight, 5x the outstanding bytes (Little's law -> ~5x effective BW).
        vf4 p[VPT]; vi4 t[VPT];
#pragma unroll
        for (int k = 0; k < VPT; ++k) p[k] = pred4[idx + k * stride];
#pragma unroll
        for (int k = 0; k < VPT; ++k) t[k] = targ4[idx + k * stride];
        asm volatile("" : "+v"(p[0]), "+v"(p[1]), "+v"(p[2]), "+v"(p[3]), "+v"(p[4]),
                          "+v"(p[5]), "+v"(p[6]), "+v"(p[7]), "+v"(p[8]), "+v"(p[9]),
                          "+v"(t[0]), "+v"(t[1]), "+v"(t[2]), "+v"(t[3]), "+v"(t[4]),
                          "+v"(t[5]), "+v"(t[6]), "+v"(t[7]), "+v"(t[8]), "+v"(t[9]));
#pragma unroll
        for (int k = 0; k < VPT; ++k) {
#pragma unroll
            for (int j = 0; j < 4; ++j) {
                float z;
                cnt += 1ull << (6 * binof(p[k][j], (float)t[k][j], z));
            }
        }
    } else {
        // Generic fallback (unused on the bench shape)
        for (int i = idx; i < nvec4; i += stride) {
            vf4 p0 = pred4[i];
            vi4 t0 = targ4[i];
#pragma unroll
            for (int j = 0; j < 4; ++j) {
                float z;
                cnt += 1ull << (6 * binof(p0[j], (float)t0[j], z));
            }
        }
    }

    int c[NBINS];
#pragma unroll
    for (int b = 0; b < NBINS; ++b) c[b] = (int)((cnt >> (6 * b)) & 63ull);

#pragma unroll
    for (int b = 0; b < NBINS; ++b) {
#pragma unroll
        for (int off = 32; off > 0; off >>= 1)
            c[b] += __shfl_down(c[b], off, 64);
    }

    const int wave = threadIdx.x >> 6;
    if ((threadIdx.x & 63) == 0) {
#pragma unroll
        for (int b = 0; b < NBINS; ++b) cred[wave][b] = c[b];
    }
    __syncthreads();
    if (threadIdx.x < NBINS) {
        int b = threadIdx.x;
        partial_c[b * GRID1 + blockIdx.x] = cred[0][b] + cred[1][b] + cred[2][b] + cred[3][b];
    }
}

// ---------------- Pass B: weighted sum with LDS weight table ----------------
__global__ __launch_bounds__(BLOCK1) void ghmc_wsum(
    const vf4* __restrict__ pred4,
    const vi4* __restrict__ targ4,
    const int* __restrict__ partial_c,   // [NBINS][GRID1]
    float* __restrict__ partial_f,       // [GRID1]
    int nvec4)
{
    __shared__ int   credb[BLOCK1 / 64][NBINS];
    __shared__ int   ctot[NBINS];
    __shared__ float wtab[NBINS];
    __shared__ float fred[BLOCK1 / 64];

    // --- prologue: reduce global counts (redundant per block; 80KB from L2/L3) ---
    {
        int cb[NBINS];
#pragma unroll
        for (int b = 0; b < NBINS; ++b) cb[b] = 0;
        for (int k = threadIdx.x; k < GRID1; k += BLOCK1) {
#pragma unroll
            for (int b = 0; b < NBINS; ++b)
                cb[b] += partial_c[b * GRID1 + k];       // coalesced per bin
        }
#pragma unroll
        for (int b = 0; b < NBINS; ++b) {
#pragma unroll
            for (int off = 32; off > 0; off >>= 1)
                cb[b] += __shfl_down(cb[b], off, 64);
        }
        const int wave = threadIdx.x >> 6;
        if ((threadIdx.x & 63) == 0) {
#pragma unroll
            for (int b = 0; b < NBINS; ++b) credb[wave][b] = cb[b];
        }
        __syncthreads();
        if (threadIdx.x < NBINS) {
            int b = threadIdx.x;
            ctot[b] = credb[0][b] + credb[1][b] + credb[2][b] + credb[3][b];
        }
        __syncthreads();
        if (threadIdx.x < NBINS) {
            int nn = 0;
#pragma unroll
            for (int k = 0; k < NBINS; ++k) nn += (ctot[k] > 0) ? 1 : 0;
            int cb0 = ctot[threadIdx.x];
            // contrib per elem = bce / (C_b * nn); fold into one f32 weight
            wtab[threadIdx.x] = (cb0 > 0)
                ? (float)(1.0 / ((double)cb0 * (double)nn)) : 0.0f;
        }
        __syncthreads();
    }

    // --- main loop: acc += wtab[bin] * bce ---
    float acc = 0.0f;

    const int idx    = blockIdx.x * BLOCK1 + threadIdx.x;
    const int stride = GRID1 * BLOCK1;

    auto elem = [&](float x, int t) {
        float z;
        int   bi = binof(x, (float)t, z);
        float sp = nlog2(1.0f + nexp2(z * LOG2E)) * LN2;              // softplus(z)
        float bce = sp - (float)t * z;
        acc += wtab[bi] * bce;                                        // 1 ds_read + 1 fmac
    };

    if (nvec4 == VPT * stride) {
        vf4 p[VPT]; vi4 t[VPT];
#pragma unroll
        for (int k = 0; k < VPT; ++k) p[k] = pred4[idx + k * stride];
#pragma unroll
        for (int k = 0; k < VPT; ++k) t[k] = targ4[idx + k * stride];
        asm volatile("" : "+v"(p[0]), "+v"(p[1]), "+v"(p[2]), "+v"(p[3]), "+v"(p[4]),
                          "+v"(p[5]), "+v"(p[6]), "+v"(p[7]), "+v"(p[8]), "+v"(p[9]),
                          "+v"(t[0]), "+v"(t[1]), "+v"(t[2]), "+v"(t[3]), "+v"(t[4]),
                          "+v"(t[5]), "+v"(t[6]), "+v"(t[7]), "+v"(t[8]), "+v"(t[9]));
#pragma unroll
        for (int k = 0; k < VPT; ++k) {
#pragma unroll
            for (int j = 0; j < 4; ++j)
                elem(p[k][j], t[k][j]);
        }
    } else {
        for (int i = idx; i < nvec4; i += stride) {
            vf4 p0 = pred4[i];
            vi4 t0 = targ4[i];
#pragma unroll
            for (int j = 0; j < 4; ++j)
                elem(p0[j], t0[j]);
        }
    }

    // --- block reduction of acc ---
#pragma unroll
    for (int off = 32; off > 0; off >>= 1)
        acc += __shfl_down(acc, off, 64);
    const int wave = threadIdx.x >> 6;
    if ((threadIdx.x & 63) == 0) fred[wave] = acc;
    __syncthreads();
    if (threadIdx.x == 0)
        partial_f[blockIdx.x] = fred[0] + fred[1] + fred[2] + fred[3];
}

// ---------------- Pass C: final reduce ----------------
__global__ __launch_bounds__(BLOCK1) void ghmc_final(
    const float* __restrict__ partial_f,   // [GRID1]
    float* __restrict__ out,
    int nblocks)
{
    __shared__ double dred[BLOCK1 / 64];

    double a = 0.0;
    for (int j = threadIdx.x; j < nblocks; j += BLOCK1)
        a += (double)partial_f[j];

#pragma unroll
    for (int off = 32; off > 0; off >>= 1)
        a += __shfl_down(a, off, 64);

    const int wave = threadIdx.x >> 6;
    if ((threadIdx.x & 63) == 0) dred[wave] = a;
    __syncthreads();
    if (threadIdx.x == 0)
        out[0] = (float)(dred[0] + dred[1] + dred[2] + dred[3]);
}

extern "C" void kernel_launch(void* const* d_in, const int* in_sizes, int n_in,
                              void* d_out, int out_size, void* d_ws, size_t ws_size,
                              hipStream_t stream)
{
    const float* pred = (const float*)d_in[0];
    const int*   targ = (const int*)d_in[1];
    float*       out  = (float*)d_out;

    const int n     = in_sizes[0];   // 20,971,520 (divisible by 4)
    const int nvec4 = n / 4;

    int*   partial_c = (int*)d_ws;                                      // 80 KB
    float* partial_f = (float*)((char*)d_ws + NBINS * GRID1 * sizeof(int));  // 8 KB

    ghmc_counts<<<GRID1, BLOCK1, 0, stream>>>(
        (const vf4*)pred, (const vi4*)targ, partial_c, nvec4);

    ghmc_wsum<<<GRID1, BLOCK1, 0, stream>>>(
        (const vf4*)pred, (const vi4*)targ, partial_c, partial_f, nvec4);

    ghmc_final<<<1, BLOCK1, 0, stream>>>(partial_f, out, GRID1);
}

// Round 11
// 199.911 us; speedup vs baseline: 1.1458x; 1.1458x over previous
//
#include <hip/hip_runtime.h>

// GHM-C loss, single pass + tiny reduce.
// loss = sum_b S_b / (count_b * n_nonempty) over nonempty bins b.
//
// R1: same-address device atomics -> cross-XCD bouncing -> per-block partials.
// R3: per-elem LDS RMW hist = 123us (lgkm chains).  R5: register select tree = 76us.
// R6: FAILED ticket fusion.  R9: exec-mask tree ~ neutral.  R10: native-trans
//   builtins bitwise-identical (were already native); 70us, VALU 37%.
// R11 (two-pass probe): stripped counts = 58us @ VALU 14.6% -> ~45us stall floor
//   in EVERY variant; wsum (L3-warm) faster than counts.
// R12: 20-load burst FAILED: VGPR 52 + AGPR traffic, occupancy 57->29%, 66-72us.
//   Lesson: extreme MLP at the cost of TLP is net-negative.
// R13 (this round): Little's law: observed 2.2-2.9 TB/s = ~4KB outstanding/CU
//   -> waves serialize {2-4 loads, full-latency wait, compute}. Fix = moderate
//   MLP x preserved TLP: 4-pair body (8 loads = 128B/thread in flight) under ONE
//   fence, keeping VGPR < 64 so 8 waves/SIMD survive. Then 2x R10's verified
//   8-elem phase groups. Per-thread element order unchanged -> absmax 0.0.

#define NBINS  10
#define GRID1  2048
#define BLOCK1 256

typedef float vf4 __attribute__((ext_vector_type(4)));
typedef int   vi4 __attribute__((ext_vector_type(4)));

#if __has_builtin(__builtin_amdgcn_exp2f)
__device__ __forceinline__ float nexp2(float a) { return __builtin_amdgcn_exp2f(a); }
#else
__device__ __forceinline__ float nexp2(float a) { return __expf(a * 0.69314718055994531f); }
#endif
#if __has_builtin(__builtin_amdgcn_logf)
__device__ __forceinline__ float nlog2(float a) { return __builtin_amdgcn_logf(a); }
#else
__device__ __forceinline__ float nlog2(float a) { return __logf(a) * 1.44269504088896341f; }
#endif

#define LOG2E 1.44269504088896341f
#define LN2   0.69314718055994531f

__global__ __launch_bounds__(BLOCK1) void ghmc_pass1(
    const vf4* __restrict__ pred4,
    const vi4* __restrict__ targ4,
    float* __restrict__ partial_s,   // [NBINS][GRID1] bin-major
    int*   __restrict__ partial_c,   // [NBINS][GRID1] bin-major
    int nvec4)
{
    __shared__ float sred[BLOCK1 / 64][NBINS];
    __shared__ int   cred[BLOCK1 / 64][NBINS];

    float s[NBINS];
#pragma unroll
    for (int b = 0; b < NBINS; ++b) s[b] = 0.0f;
    unsigned long long cnt = 0;   // 10 x 6-bit packed counts; max 40/bin/thread < 63

    const int idx    = blockIdx.x * BLOCK1 + threadIdx.x;
    const int stride = GRID1 * BLOCK1;

    // R10's verified 8-elem phase group: 8 sigmoid chains co-live, then 8
    // bin+bce, then cndmask scatter-add in elem order (bitwise-stable).
    auto group8 = [&](vf4 p0, vi4 t0, vf4 p1, vi4 t1) {
        float x[8], tf[8];
#pragma unroll
        for (int j = 0; j < 4; ++j) {
            x[j]     = p0[j];  tf[j]     = (float)t0[j];
            x[4 + j] = p1[j];  tf[4 + j] = (float)t1[j];
        }
        float z[8];
#pragma unroll
        for (int j = 0; j < 8; ++j)
            z[j] = __builtin_amdgcn_rcpf(1.0f + nexp2(-x[j] * LOG2E));   // sigmoid
        asm volatile("" : "+v"(z[0]), "+v"(z[1]), "+v"(z[2]), "+v"(z[3]),
                         "+v"(z[4]), "+v"(z[5]), "+v"(z[6]), "+v"(z[7]));
        int bi[8]; float bce[8];
#pragma unroll
        for (int j = 0; j < 8; ++j) {
            float g = fabsf(z[j] - tf[j]);                               // [0,1]
            int   b = (int)(g * 10.0f);
            bi[j]   = b > (NBINS - 1) ? (NBINS - 1) : b;
            float sp = nlog2(1.0f + nexp2(z[j] * LOG2E)) * LN2;          // softplus(z)
            bce[j]  = sp - tf[j] * z[j];
        }
#pragma unroll
        for (int j = 0; j < 8; ++j) {
#pragma unroll
            for (int b = 0; b < NBINS; ++b)
                s[b] += (bi[j] == b) ? bce[j] : 0.0f;
            cnt += 1ull << (6 * bi[j]);
        }
    };

    int i = idx;
    // 4-pair body: 8 independent dwordx4 loads issued under one fence
    // (128 B/thread in flight); bench shape runs this twice + one 2-pair tail.
    for (; i + 3 * stride < nvec4; i += 4 * stride) {
        vf4 p0 = pred4[i];
        vi4 t0 = targ4[i];
        vf4 p1 = pred4[i + stride];
        vi4 t1 = targ4[i + stride];
        vf4 p2 = pred4[i + 2 * stride];
        vi4 t2 = targ4[i + 2 * stride];
        vf4 p3 = pred4[i + 3 * stride];
        vi4 t3 = targ4[i + 3 * stride];
        asm volatile("" : "+v"(p0), "+v"(t0), "+v"(p1), "+v"(t1),
                          "+v"(p2), "+v"(t2), "+v"(p3), "+v"(t3));
        group8(p0, t0, p1, t1);      // elems k, k+1  (order unchanged)
        group8(p2, t2, p3, t3);      // elems k+2, k+3
    }
    for (; i + stride < nvec4; i += 2 * stride) {
        vf4 p0 = pred4[i];
        vi4 t0 = targ4[i];
        vf4 p1 = pred4[i + stride];
        vi4 t1 = targ4[i + stride];
        asm volatile("" : "+v"(p0), "+v"(t0), "+v"(p1), "+v"(t1));
        group8(p0, t0, p1, t1);
    }
    if (i < nvec4) {   // generic tail (unused on bench shape)
        vf4 p0 = pred4[i];
        vi4 t0 = targ4[i];
#pragma unroll
        for (int j = 0; j < 4; ++j) {
            float tfj = (float)t0[j];
            float zj  = __builtin_amdgcn_rcpf(1.0f + nexp2(-p0[j] * LOG2E));
            float g   = fabsf(zj - tfj);
            int   b   = (int)(g * 10.0f);
            b = b > (NBINS - 1) ? (NBINS - 1) : b;
            float bc  = nlog2(1.0f + nexp2(zj * LOG2E)) * LN2 - tfj * zj;
#pragma unroll
            for (int bb = 0; bb < NBINS; ++bb)
                s[bb] += (b == bb) ? bc : 0.0f;
            cnt += 1ull << (6 * b);
        }
    }

    // unpack packed counts
    int c[NBINS];
#pragma unroll
    for (int b = 0; b < NBINS; ++b) c[b] = (int)((cnt >> (6 * b)) & 63ull);

    // wave(64) tree reduction
#pragma unroll
    for (int b = 0; b < NBINS; ++b) {
#pragma unroll
        for (int off = 32; off > 0; off >>= 1) {
            s[b] += __shfl_down(s[b], off, 64);
            c[b] += __shfl_down(c[b], off, 64);
        }
    }

    const int wave = threadIdx.x >> 6;
    if ((threadIdx.x & 63) == 0) {
#pragma unroll
        for (int b = 0; b < NBINS; ++b) { sred[wave][b] = s[b]; cred[wave][b] = c[b]; }
    }
    __syncthreads();
    if (threadIdx.x < NBINS) {
        int b = threadIdx.x;
        partial_s[b * GRID1 + blockIdx.x] = sred[0][b] + sred[1][b] + sred[2][b] + sred[3][b];
        partial_c[b * GRID1 + blockIdx.x] = cred[0][b] + cred[1][b] + cred[2][b] + cred[3][b];
    }
}

#define BLOCK2 1024

__global__ __launch_bounds__(BLOCK2) void ghmc_pass2(
    const float* __restrict__ partial_s,   // [NBINS][GRID1]
    const int*   __restrict__ partial_c,
    float* __restrict__ out,
    int nblocks)
{
    double as[NBINS];
    int    ac[NBINS];
#pragma unroll
    for (int b = 0; b < NBINS; ++b) { as[b] = 0.0; ac[b] = 0; }

    for (int j = threadIdx.x; j < nblocks; j += BLOCK2) {
#pragma unroll
        for (int b = 0; b < NBINS; ++b) {
            as[b] += (double)partial_s[b * nblocks + j];   // coalesced per bin
            ac[b] += partial_c[b * nblocks + j];
        }
    }

#pragma unroll
    for (int b = 0; b < NBINS; ++b) {
#pragma unroll
        for (int off = 32; off > 0; off >>= 1) {
            as[b] += __shfl_down(as[b], off, 64);
            ac[b] += __shfl_down(ac[b], off, 64);
        }
    }

    __shared__ double sds[BLOCK2 / 64][NBINS];
    __shared__ int    sdc[BLOCK2 / 64][NBINS];
    int wave = threadIdx.x >> 6;
    if ((threadIdx.x & 63) == 0) {
#pragma unroll
        for (int b = 0; b < NBINS; ++b) { sds[wave][b] = as[b]; sdc[wave][b] = ac[b]; }
    }
    __syncthreads();

    if (threadIdx.x == 0) {
        int nn = 0;
        double acc = 0.0;
#pragma unroll
        for (int b = 0; b < NBINS; ++b) {
            double sb = 0.0;
            int    cb = 0;
#pragma unroll
            for (int w = 0; w < BLOCK2 / 64; ++w) { sb += sds[w][b]; cb += sdc[w][b]; }
            if (cb > 0) { nn += 1; acc += sb / (double)cb; }
        }
        out[0] = (float)(acc / (double)(nn > 0 ? nn : 1));
    }
}

extern "C" void kernel_launch(void* const* d_in, const int* in_sizes, int n_in,
                              void* d_out, int out_size, void* d_ws, size_t ws_size,
                              hipStream_t stream)
{
    const float* pred = (const float*)d_in[0];
    const int*   targ = (const int*)d_in[1];
    float*       out  = (float*)d_out;

    const int n     = in_sizes[0];   // 20,971,520 (divisible by 4)
    const int nvec4 = n / 4;

    float* partial_s = (float*)d_ws;                                  // NBINS*GRID1 floats
    int*   partial_c = (int*)((char*)d_ws + GRID1 * NBINS * sizeof(float));

    ghmc_pass1<<<GRID1, BLOCK1, 0, stream>>>(
        (const vf4*)pred, (const vi4*)targ, partial_s, partial_c, nvec4);

    ghmc_pass2<<<1, BLOCK2, 0, stream>>>(partial_s, partial_c, out, GRID1);
}

// Round 12
// 199.811 us; speedup vs baseline: 1.1464x; 1.0005x over previous
//
#include <hip/hip_runtime.h>

// GHM-C loss, single pass + tiny reduce.
// loss = sum_b S_b / (count_b * n_nonempty) over nonempty bins b.
//
// R1: same-address device atomics -> cross-XCD bouncing -> per-block partials.
// R3: per-elem LDS RMW hist = 123us.  R5: select tree 76us.  R6: FAILED ticket.
// R10: native-trans builtins bitwise-identical -> were already native; 70us.
// R11: stripped 14-instr kernel STILL 58us -> ~45-50us vmcnt-stall floor in all.
// R12: 20-load VGPR burst: occupancy 57->29%, REGRESSED.  R13: 8-load burst:
//   compiler sank loads again (VGPR 40). Conclusion: VGPR prefetch is a dead
//   end -- compiler sinks it or occupancy dies.
// R14 (this round): prefetch depth WITHOUT VGPRs: global_load_lds direct-to-LDS
//   DMA (zero dest regs in flight; compiler never auto-emits it). Minimum T3
//   2-phase pipeline: stage tile t+1 -> buf^1 while computing tile t from buf;
//   one __syncthreads()/tile (its vmcnt-drain IS the buffer-ready wait, issued
//   ~500cy of compute after the stage). Outstanding bytes/CU: ~4KB -> 64KB.
//   LDS 16.5KB x 8 blocks = 132 <= 160KB; VGPR stays ~36 -> occupancy intact.
//   Element order per thread unchanged -> bitwise-identical (absmax 0.0).

#define NBINS  10
#define GRID1  2048
#define BLOCK1 256

typedef float vf4 __attribute__((ext_vector_type(4)));
typedef int   vi4 __attribute__((ext_vector_type(4)));

#if __has_builtin(__builtin_amdgcn_exp2f)
__device__ __forceinline__ float nexp2(float a) { return __builtin_amdgcn_exp2f(a); }
#else
__device__ __forceinline__ float nexp2(float a) { return __expf(a * 0.69314718055994531f); }
#endif
#if __has_builtin(__builtin_amdgcn_logf)
__device__ __forceinline__ float nlog2(float a) { return __builtin_amdgcn_logf(a); }
#else
__device__ __forceinline__ float nlog2(float a) { return __logf(a) * 1.44269504088896341f; }
#endif

#define LOG2E 1.44269504088896341f
#define LN2   0.69314718055994531f

// Direct-to-LDS 16B DMA: per-lane global src, WAVE-UNIFORM lds base + lane*16.
#define GLOAD16(gsrc, ldst)                                                \
    __builtin_amdgcn_global_load_lds(                                      \
        (const __attribute__((address_space(1))) void*)(gsrc),             \
        (__attribute__((address_space(3))) void*)(ldst), 16, 0, 0)

__global__ __launch_bounds__(BLOCK1) void ghmc_pass1(
    const vf4* __restrict__ pred4,
    const vi4* __restrict__ targ4,
    float* __restrict__ partial_s,   // [NBINS][GRID1] bin-major
    int*   __restrict__ partial_c,   // [NBINS][GRID1] bin-major
    int nvec4)
{
    __shared__ vf4  plds[2][BLOCK1];     // 2 x 4 KB
    __shared__ vi4  tlds[2][BLOCK1];     // 2 x 4 KB
    __shared__ float sred[BLOCK1 / 64][NBINS];
    __shared__ int   cred[BLOCK1 / 64][NBINS];

    float s[NBINS];
#pragma unroll
    for (int b = 0; b < NBINS; ++b) s[b] = 0.0f;
    unsigned long long cnt = 0;   // 10 x 6-bit packed counts; max 40/bin/thread < 63

    const int tid    = threadIdx.x;
    const int wbase  = tid & ~63;           // wave-uniform LDS slot base
    const int g0     = blockIdx.x * BLOCK1 + tid;
    const int stride = GRID1 * BLOCK1;
    const int ntiles = nvec4 / stride;      // 10 on the bench shape

    // R10's verified phase group, 4-wide: sigmoid chains co-live, then bin+bce,
    // then cndmask scatter-add in element order (bitwise-stable vs R10/R13).
    auto group4 = [&](vf4 p, vi4 t) {
        float z[4], tf[4];
#pragma unroll
        for (int j = 0; j < 4; ++j) {
            tf[j] = (float)t[j];
            z[j]  = __builtin_amdgcn_rcpf(1.0f + nexp2(-p[j] * LOG2E));   // sigmoid
        }
        asm volatile("" : "+v"(z[0]), "+v"(z[1]), "+v"(z[2]), "+v"(z[3]));
        int bi[4]; float bce[4];
#pragma unroll
        for (int j = 0; j < 4; ++j) {
            float g = fabsf(z[j] - tf[j]);                                // [0,1]
            int   b = (int)(g * 10.0f);
            bi[j]   = b > (NBINS - 1) ? (NBINS - 1) : b;
            float sp = nlog2(1.0f + nexp2(z[j] * LOG2E)) * LN2;           // softplus(z)
            bce[j]  = sp - tf[j] * z[j];
        }
#pragma unroll
        for (int j = 0; j < 4; ++j) {
#pragma unroll
            for (int b = 0; b < NBINS; ++b)
                s[b] += (bi[j] == b) ? bce[j] : 0.0f;
            cnt += 1ull << (6 * bi[j]);
        }
    };

    if (ntiles > 0) {
        // prologue: stage tile 0 into buf 0 (DMA), wait, sync
        GLOAD16(&pred4[g0], &plds[0][wbase]);
        GLOAD16(&targ4[g0], &tlds[0][wbase]);
        __syncthreads();   // compiler drains vmcnt(0) before s_barrier

        int cur = 0;
        for (int t = 0; t < ntiles; ++t) {
            if (t + 1 < ntiles) {               // stage next tile, fire-and-forget
                const int gn = g0 + (t + 1) * stride;
                GLOAD16(&pred4[gn], &plds[cur ^ 1][wbase]);
                GLOAD16(&targ4[gn], &tlds[cur ^ 1][wbase]);
            }
            group4(plds[cur][tid], tlds[cur][tid]);   // ~500cy compute from LDS
            __syncthreads();   // vmcnt drain = next buffer ready; also guards reuse
            cur ^= 1;
        }
    }
    // generic tail (unused on the bench shape): plain loads
    for (int i = g0 + ntiles * stride; i < nvec4; i += stride) {
        vf4 p0 = pred4[i];
        vi4 t0 = targ4[i];
        group4(p0, t0);
    }

    // unpack packed counts
    int c[NBINS];
#pragma unroll
    for (int b = 0; b < NBINS; ++b) c[b] = (int)((cnt >> (6 * b)) & 63ull);

    // wave(64) tree reduction
#pragma unroll
    for (int b = 0; b < NBINS; ++b) {
#pragma unroll
        for (int off = 32; off > 0; off >>= 1) {
            s[b] += __shfl_down(s[b], off, 64);
            c[b] += __shfl_down(c[b], off, 64);
        }
    }

    const int wave = tid >> 6;
    if ((tid & 63) == 0) {
#pragma unroll
        for (int b = 0; b < NBINS; ++b) { sred[wave][b] = s[b]; cred[wave][b] = c[b]; }
    }
    __syncthreads();
    if (tid < NBINS) {
        int b = tid;
        partial_s[b * GRID1 + blockIdx.x] = sred[0][b] + sred[1][b] + sred[2][b] + sred[3][b];
        partial_c[b * GRID1 + blockIdx.x] = cred[0][b] + cred[1][b] + cred[2][b] + cred[3][b];
    }
}

#define BLOCK2 1024

__global__ __launch_bounds__(BLOCK2) void ghmc_pass2(
    const float* __restrict__ partial_s,   // [NBINS][GRID1]
    const int*   __restrict__ partial_c,
    float* __restrict__ out,
    int nblocks)
{
    double as[NBINS];
    int    ac[NBINS];
#pragma unroll
    for (int b = 0; b < NBINS; ++b) { as[b] = 0.0; ac[b] = 0; }

    for (int j = threadIdx.x; j < nblocks; j += BLOCK2) {
#pragma unroll
        for (int b = 0; b < NBINS; ++b) {
            as[b] += (double)partial_s[b * nblocks + j];   // coalesced per bin
            ac[b] += partial_c[b * nblocks + j];
        }
    }

#pragma unroll
    for (int b = 0; b < NBINS; ++b) {
#pragma unroll
        for (int off = 32; off > 0; off >>= 1) {
            as[b] += __shfl_down(as[b], off, 64);
            ac[b] += __shfl_down(ac[b], off, 64);
        }
    }

    __shared__ double sds[BLOCK2 / 64][NBINS];
    __shared__ int    sdc[BLOCK2 / 64][NBINS];
    int wave = threadIdx.x >> 6;
    if ((threadIdx.x & 63) == 0) {
#pragma unroll
        for (int b = 0; b < NBINS; ++b) { sds[wave][b] = as[b]; sdc[wave][b] = ac[b]; }
    }
    __syncthreads();

    if (threadIdx.x == 0) {
        int nn = 0;
        double acc = 0.0;
#pragma unroll
        for (int b = 0; b < NBINS; ++b) {
            double sb = 0.0;
            int    cb = 0;
#pragma unroll
            for (int w = 0; w < BLOCK2 / 64; ++w) { sb += sds[w][b]; cb += sdc[w][b]; }
            if (cb > 0) { nn += 1; acc += sb / (double)cb; }
        }
        out[0] = (float)(acc / (double)(nn > 0 ? nn : 1));
    }
}

extern "C" void kernel_launch(void* const* d_in, const int* in_sizes, int n_in,
                              void* d_out, int out_size, void* d_ws, size_t ws_size,
                              hipStream_t stream)
{
    const float* pred = (const float*)d_in[0];
    const int*   targ = (const int*)d_in[1];
    float*       out  = (float*)d_out;

    const int n     = in_sizes[0];   // 20,971,520 (divisible by 4)
    const int nvec4 = n / 4;

    float* partial_s = (float*)d_ws;                                  // NBINS*GRID1 floats
    int*   partial_c = (int*)((char*)d_ws + GRID1 * NBINS * sizeof(float));

    ghmc_pass1<<<GRID1, BLOCK1, 0, stream>>>(
        (const vf4*)pred, (const vi4*)targ, partial_s, partial_c, nvec4);

    ghmc_pass2<<<1, BLOCK2, 0, stream>>>(partial_s, partial_c, out, GRID1);
}

// Round 13
// 196.304 us; speedup vs baseline: 1.1669x; 1.0179x over previous
//
#include <hip/hip_runtime.h>

// GHM-C loss, single pass + tiny reduce.
// loss = sum_b S_b / (count_b * n_nonempty) over nonempty bins b.
//
// R1: same-address device atomics -> cross-XCD bouncing -> per-block partials.
// R3: per-elem LDS RMW hist = 123us.  R5: select tree 76us.  R6: FAILED ticket.
// R10: native-trans builtins bitwise-identical; 70us.  R11: stripped kernel
//   still 58us -> ~45-50us stall floor.  R12/R13: VGPR prefetch dead end
//   (compiler sinks it or occupancy dies).
// R14: LDS DMA double-buffer + per-tile __syncthreads: structure landed
//   (LDS=16.9KB) but NEUTRAL -- syncthreads emits s_waitcnt vmcnt(0) before
//   s_barrier (m97), draining the just-issued prefetch EVERY tile. This is the
//   guide's "counted-vmcnt vs drain0" lesson (m218: +38-73% for counted).
// R15 (this round): barriers removed entirely -- each wave reads ONLY its own
//   staged segment (no cross-wave sharing), so each wave runs a private
//   double-buffered pipeline with counted s_waitcnt vmcnt(2) (0 only at last
//   tile). ds_read via inline asm so the compiler can't inject its own drain
//   (+ sched_barrier(0) fences, rule 18). vmcnt retires in order (m135) ->
//   vmcnt(2) == "my tile landed, next two still flying". Fully unrolled
//   10-tile loop (bench shape) -> literal wait counts. Element order
//   unchanged -> bitwise-identical (absmax 0.0).

#define NBINS  10
#define GRID1  2048
#define BLOCK1 256

typedef float vf4 __attribute__((ext_vector_type(4)));
typedef int   vi4 __attribute__((ext_vector_type(4)));

#if __has_builtin(__builtin_amdgcn_exp2f)
__device__ __forceinline__ float nexp2(float a) { return __builtin_amdgcn_exp2f(a); }
#else
__device__ __forceinline__ float nexp2(float a) { return __expf(a * 0.69314718055994531f); }
#endif
#if __has_builtin(__builtin_amdgcn_logf)
__device__ __forceinline__ float nlog2(float a) { return __builtin_amdgcn_logf(a); }
#else
__device__ __forceinline__ float nlog2(float a) { return __logf(a) * 1.44269504088896341f; }
#endif

#define LOG2E 1.44269504088896341f
#define LN2   0.69314718055994531f

// Direct-to-LDS 16B DMA: per-lane global src, WAVE-UNIFORM lds base + lane*16.
#define GLOAD16(gsrc, ldst)                                                \
    __builtin_amdgcn_global_load_lds(                                      \
        (const __attribute__((address_space(1))) void*)(gsrc),             \
        (__attribute__((address_space(3))) void*)(ldst), 16, 0, 0)

#define LDSOFF(ptr) ((unsigned)(unsigned long long)                        \
    (__attribute__((address_space(3))) void*)(ptr))

__global__ __launch_bounds__(BLOCK1) void ghmc_pass1(
    const vf4* __restrict__ pred4,
    const vi4* __restrict__ targ4,
    float* __restrict__ partial_s,   // [NBINS][GRID1] bin-major
    int*   __restrict__ partial_c,   // [NBINS][GRID1] bin-major
    int nvec4)
{
    __shared__ vf4  plds[2][BLOCK1];     // 2 x 4 KB
    __shared__ vi4  tlds[2][BLOCK1];     // 2 x 4 KB
    __shared__ float sred[BLOCK1 / 64][NBINS];
    __shared__ int   cred[BLOCK1 / 64][NBINS];

    float s[NBINS];
#pragma unroll
    for (int b = 0; b < NBINS; ++b) s[b] = 0.0f;
    unsigned long long cnt = 0;   // 10 x 6-bit packed counts; max 40/bin/thread < 63

    const int tid    = threadIdx.x;
    const int wbase  = tid & ~63;           // wave-uniform LDS slot base
    const int g0     = blockIdx.x * BLOCK1 + tid;
    const int stride = GRID1 * BLOCK1;
    const int ntiles = nvec4 / stride;      // 10 on the bench shape

    // R10/R14's verified phase group, 4-wide (math + accumulation order
    // identical to all passing rounds -> bitwise-stable).
    auto group4 = [&](vf4 p, vi4 t) {
        float z[4], tf[4];
#pragma unroll
        for (int j = 0; j < 4; ++j) {
            tf[j] = (float)t[j];
            z[j]  = __builtin_amdgcn_rcpf(1.0f + nexp2(-p[j] * LOG2E));   // sigmoid
        }
        asm volatile("" : "+v"(z[0]), "+v"(z[1]), "+v"(z[2]), "+v"(z[3]));
        int bi[4]; float bce[4];
#pragma unroll
        for (int j = 0; j < 4; ++j) {
            float g = fabsf(z[j] - tf[j]);                                // [0,1]
            int   b = (int)(g * 10.0f);
            bi[j]   = b > (NBINS - 1) ? (NBINS - 1) : b;
            float sp = nlog2(1.0f + nexp2(z[j] * LOG2E)) * LN2;           // softplus(z)
            bce[j]  = sp - tf[j] * z[j];
        }
#pragma unroll
        for (int j = 0; j < 4; ++j) {
#pragma unroll
            for (int b = 0; b < NBINS; ++b)
                s[b] += (bi[j] == b) ? bce[j] : 0.0f;
            cnt += 1ull << (6 * bi[j]);
        }
    };

    if (ntiles == 10 && nvec4 == 10 * stride) {
        const unsigned pbase = LDSOFF(&plds[0][0]);
        const unsigned tbase = LDSOFF(&tlds[0][0]);

        // prologue: stage tiles 0 and 1 (4 loads in flight; no VGPR held)
        GLOAD16(&pred4[g0],          &plds[0][wbase]);
        GLOAD16(&targ4[g0],          &tlds[0][wbase]);
        GLOAD16(&pred4[g0 + stride], &plds[1][wbase]);
        GLOAD16(&targ4[g0 + stride], &tlds[1][wbase]);

        // Private per-wave pipeline: NO barriers. Counted waits only.
        // vmcnt counts this wave's outstanding VMEM in issue order:
        // at tile t, allowing 2 outstanding == tiles t+1,t+2 still flying.
#pragma unroll
        for (int t = 0; t < 10; ++t) {
            if (t < 9) asm volatile("s_waitcnt vmcnt(2)" ::: "memory");
            else       asm volatile("s_waitcnt vmcnt(0)" ::: "memory");
            __builtin_amdgcn_sched_barrier(0);

            vf4 p; vi4 tt;
            const unsigned ap = pbase + (unsigned)(((t & 1) * BLOCK1 + tid) * 16);
            const unsigned at = tbase + (unsigned)(((t & 1) * BLOCK1 + tid) * 16);
            asm volatile("ds_read_b128 %0, %1" : "=v"(p)  : "v"(ap));
            asm volatile("ds_read_b128 %0, %1" : "=v"(tt) : "v"(at));
            asm volatile("s_waitcnt lgkmcnt(0)" ::: "memory");
            __builtin_amdgcn_sched_barrier(0);

            if (t + 2 < 10) {   // refill the buffer we just finished reading
                const int gn = g0 + (t + 2) * stride;
                GLOAD16(&pred4[gn], &plds[t & 1][wbase]);
                GLOAD16(&targ4[gn], &tlds[t & 1][wbase]);
            }
            group4(p, tt);
        }
    } else {
        // generic fallback (unused on the bench shape): plain loads
        for (int i = g0; i < nvec4; i += stride) {
            vf4 p0 = pred4[i];
            vi4 t0 = targ4[i];
            group4(p0, t0);
        }
    }

    // unpack packed counts
    int c[NBINS];
#pragma unroll
    for (int b = 0; b < NBINS; ++b) c[b] = (int)((cnt >> (6 * b)) & 63ull);

    // wave(64) tree reduction
#pragma unroll
    for (int b = 0; b < NBINS; ++b) {
#pragma unroll
        for (int off = 32; off > 0; off >>= 1) {
            s[b] += __shfl_down(s[b], off, 64);
            c[b] += __shfl_down(c[b], off, 64);
        }
    }

    const int wave = tid >> 6;
    if ((tid & 63) == 0) {
#pragma unroll
        for (int b = 0; b < NBINS; ++b) { sred[wave][b] = s[b]; cred[wave][b] = c[b]; }
    }
    __syncthreads();
    if (tid < NBINS) {
        int b = tid;
        partial_s[b * GRID1 + blockIdx.x] = sred[0][b] + sred[1][b] + sred[2][b] + sred[3][b];
        partial_c[b * GRID1 + blockIdx.x] = cred[0][b] + cred[1][b] + cred[2][b] + cred[3][b];
    }
}

#define BLOCK2 1024

__global__ __launch_bounds__(BLOCK2) void ghmc_pass2(
    const float* __restrict__ partial_s,   // [NBINS][GRID1]
    const int*   __restrict__ partial_c,
    float* __restrict__ out,
    int nblocks)
{
    double as[NBINS];
    int    ac[NBINS];
#pragma unroll
    for (int b = 0; b < NBINS; ++b) { as[b] = 0.0; ac[b] = 0; }

    for (int j = threadIdx.x; j < nblocks; j += BLOCK2) {
#pragma unroll
        for (int b = 0; b < NBINS; ++b) {
            as[b] += (double)partial_s[b * nblocks + j];   // coalesced per bin
            ac[b] += partial_c[b * nblocks + j];
        }
    }

#pragma unroll
    for (int b = 0; b < NBINS; ++b) {
#pragma unroll
        for (int off = 32; off > 0; off >>= 1) {
            as[b] += __shfl_down(as[b], off, 64);
            ac[b] += __shfl_down(ac[b], off, 64);
        }
    }

    __shared__ double sds[BLOCK2 / 64][NBINS];
    __shared__ int    sdc[BLOCK2 / 64][NBINS];
    int wave = threadIdx.x >> 6;
    if ((threadIdx.x & 63) == 0) {
#pragma unroll
        for (int b = 0; b < NBINS; ++b) { sds[wave][b] = as[b]; sdc[wave][b] = ac[b]; }
    }
    __syncthreads();

    if (threadIdx.x == 0) {
        int nn = 0;
        double acc = 0.0;
#pragma unroll
        for (int b = 0; b < NBINS; ++b) {
            double sb = 0.0;
            int    cb = 0;
#pragma unroll
            for (int w = 0; w < BLOCK2 / 64; ++w) { sb += sds[w][b]; cb += sdc[w][b]; }
            if (cb > 0) { nn += 1; acc += sb / (double)cb; }
        }
        out[0] = (float)(acc / (double)(nn > 0 ? nn : 1));
    }
}

extern "C" void kernel_launch(void* const* d_in, const int* in_sizes, int n_in,
                              void* d_out, int out_size, void* d_ws, size_t ws_size,
                              hipStream_t stream)
{
    const float* pred = (const float*)d_in[0];
    const int*   targ = (const int*)d_in[1];
    float*       out  = (float*)d_out;

    const int n     = in_sizes[0];   // 20,971,520 (divisible by 4)
    const int nvec4 = n / 4;

    float* partial_s = (float*)d_ws;                                  // NBINS*GRID1 floats
    int*   partial_c = (int*)((char*)d_ws + GRID1 * NBINS * sizeof(float));

    ghmc_pass1<<<GRID1, BLOCK1, 0, stream>>>(
        (const vf4*)pred, (const vi4*)targ, partial_s, partial_c, nvec4);

    ghmc_pass2<<<1, BLOCK2, 0, stream>>>(partial_s, partial_c, out, GRID1);
}